// Round 9
// baseline (45.722 us; speedup 1.0000x reference)
//
#include <hip/hip_runtime.h>

#define G_GEN 65
#define FEAT  8192     // 32*16*16
#define NSTAT 32       // stats blocks
#define NFILL 2016     // fill blocks; NSTAT+NFILL = 2048 = exact full-device residency

typedef float f32x4 __attribute__((ext_vector_type(4)));
typedef int   i32x4 __attribute__((ext_vector_type(4)));

// Kernel A (R8 structure, wave-store-aligned chunks):
//  bid <  32 : per-feature stats -> ws_val/ws_cross + base rows
//  bid >= 32 : zero-fill a contiguous chunk, chunked in 1KB (64-f4) units so every
//              64-lane x 16B wave store is a full, aligned 1KB burst (no partial
//              cache lines -> no L2 read-for-ownership).
__global__ void __launch_bounds__(256) kA(
    const float* __restrict__ x, const float* __restrict__ lambdas,
    float* __restrict__ ws_val, int* __restrict__ ws_cross,
    float* __restrict__ out)
{
    const int bid = blockIdx.x;
    const int t   = threadIdx.x;

    if (bid < NSTAT) {
        const int f = bid * 256 + t;          // coalesced across lanes
        float c = x[f];                       // generator 0 = center
        float r = 0.f;
        #pragma unroll 8
        for (int g = 1; g < G_GEN; ++g) r += fabsf(x[g * FEAT + f]);
        float l = c - r, u = c + r;
        bool zero_m = (u <= 0.f);
        bool cross  = (!zero_m) && (l < 0.f);
        float d     = u - l;
        float denom = (d > 0.f) ? d : 1.f;
        float slope = u / denom;
        float lam   = lambdas[f];
        float val   = (lam >= slope) ? (-l * lam * 0.5f) : (u * (1.f - lam) * 0.5f);
        val = cross ? val : 0.f;
        float scale = zero_m ? 0.f : (cross ? lam : 1.f);
        ws_val[f]   = val;
        ws_cross[f] = cross ? 1 : 0;
        out[f] = c * scale + val;             // g == 0 row
        #pragma unroll 8
        for (int g = 1; g < G_GEN; ++g)
            out[g * FEAT + f] = x[g * FEAT + f] * scale;  // 2nd x read: L2-hot
    } else {
        // zero-fill: 262144 units of 64 f4 (1KB) over 2016 blocks; q=130, r=64.
        // lo/hi in f4; lo is a multiple of 64 f4 -> every wave store 1KB-aligned.
        const int  j  = bid - NSTAT;
        const long lo = ((long)j * 130 + (j < 64 ? j : 64)) << 6;
        const long hi = lo + ((130 + (j < 64 ? 1 : 0)) << 6);
        f32x4* eps = reinterpret_cast<f32x4*>(out + (size_t)G_GEN * FEAT);
        f32x4 z = {0.f, 0.f, 0.f, 0.f};
        for (long i = lo + t; i < hi; i += 256)
            eps[i] = z;
    }
}

// Kernel B: 1024-thread scan (wave64 shfl + 16 wave-sums) + scatter.
__global__ void __launch_bounds__(1024) kB(
    const float* __restrict__ ws_val,
    const int* __restrict__ ws_cross,
    float* __restrict__ out)
{
    __shared__ int wsum[16];
    const int t = threadIdx.x;
    const int base = t * 8;                   // 8 contiguous features per thread
    const i32x4* cp = reinterpret_cast<const i32x4*>(ws_cross + base);
    i32x4 c0 = cp[0], c1 = cp[1];
    int flags[8] = {c0[0], c0[1], c0[2], c0[3], c1[0], c1[1], c1[2], c1[3]};
    int local = 0;
    #pragma unroll
    for (int i = 0; i < 8; ++i) local += flags[i];

    const int lane = t & 63, w = t >> 6;      // 16 waves of 64
    int v = local;                            // wave-inclusive scan
    #pragma unroll
    for (int off = 1; off < 64; off <<= 1) {
        int n = __shfl_up(v, off, 64);
        if (lane >= off) v += n;
    }
    if (lane == 63) wsum[w] = v;
    __syncthreads();
    int wpre = 0;
    for (int j = 0; j < w; ++j) wpre += wsum[j];   // broadcast LDS reads
    int rank = wpre + v - local;              // exclusive prefix for this chunk

    const f32x4* vp = reinterpret_cast<const f32x4*>(ws_val + base);
    f32x4 v0 = vp[0], v1 = vp[1];
    float vals[8] = {v0[0], v0[1], v0[2], v0[3], v1[0], v1[1], v1[2], v1[3]};
    #pragma unroll
    for (int i = 0; i < 8; ++i) {
        if (flags[i]) {
            out[(size_t)(G_GEN + rank) * FEAT + (base + i)] = vals[i];
            ++rank;
        }
    }
}

extern "C" void kernel_launch(void* const* d_in, const int* in_sizes, int n_in,
                              void* d_out, int out_size, void* d_ws, size_t ws_size,
                              hipStream_t stream) {
    const float* x       = (const float*)d_in[0];
    const float* lambdas = (const float*)d_in[1];
    float* out = (float*)d_out;

    float* ws_val   = (float*)d_ws;
    int*   ws_cross = (int*)(ws_val + FEAT);

    kA<<<NSTAT + NFILL, 256, 0, stream>>>(x, lambdas, ws_val, ws_cross, out);
    kB<<<1, 1024, 0, stream>>>(ws_val, ws_cross, out);
}